// Round 6
// baseline (46.999 us; speedup 1.0000x reference)
//
#include <hip/hip_runtime.h>
#include <hip/hip_fp16.h>

#define BINS 30
#define BLOCK 256
#define GRID 1280           // 5 blocks/CU (30 KB LDS each) x 256 CU = one round
#define GSTRIDE 32          // one 128B cache line per global accumulator slot

__device__ __forceinline__ float fast_exp2(float x){ return __builtin_amdgcn_exp2f(x); }
__device__ __forceinline__ float fast_log2(float x){ return __builtin_amdgcn_logf(x); }
__device__ __forceinline__ float fast_rcp (float x){ return __builtin_amdgcn_rcpf(x); }

#define LOG2E 1.4426950408889634f
#define LN2   0.6931471805599453f

// Per element: y = (t?-x:x);  g = sigmoid(y) = |sigmoid(x)-t|;
// bin = min(int(g*30),29);  bce = max(y,0)+log1p(exp(-|y|)) = -ln(1-g).
// Accumulate {cnt,sum} as a packed __half2 in a THREAD-PRIVATE LDS column:
// ds_read_b32 + v_pk_add_f16 + ds_write_b32, race-free, conflict-free
// (b32 columns -> 2 lanes/bank, free), 30 KB LDS -> 5 blocks/CU.
// f16 exactness: per-block per-bin counts stay well under 2048 (exact
// integer range); sums tolerate ~1e-3 relative vs the 2% loss budget.
__global__ __launch_bounds__(BLOCK, 5) void ghm_pass1(
    const float4* __restrict__ preds4, const float4* __restrict__ targets4,
    long n4, long n_total,
    float* __restrict__ gCnt, float* __restrict__ gSum)  // padded slots
{
    __shared__ __half2 hist[BINS][BLOCK];   // 30 KB: {cnt_h, sum_h} per bin/thread

    const int tid = threadIdx.x;
    const __half2 zero2 = __halves2half2(__ushort_as_half(0), __ushort_as_half(0));
    #pragma unroll
    for (int b = 0; b < BINS; ++b) hist[b][tid] = zero2;
    __syncthreads();

    const __half one_h = __float2half_rn(1.0f);

    auto do4 = [&](float4 p, float4 t) {
        #pragma unroll
        for (int j = 0; j < 4; ++j) {
            float x  = (&p.x)[j];
            float tt = (&t.x)[j];
            float y  = __builtin_fmaf(x * tt, -2.0f, x);   // t ? -x : x
            float e  = fast_exp2(fabsf(y) * -LOG2E);       // exp(-|y|)
            float d  = 1.0f + e;
            float r  = fast_rcp(d);
            float g  = (y >= 0.0f) ? r : e * r;            // sigmoid(y)
            int   b  = (int)(g * 30.0f);
            b = (b > BINS - 1) ? BINS - 1 : b;
            float bce = fmaxf(y, 0.0f) + fast_log2(d) * LN2;
            __half2 inc = __halves2half2(one_h, __float2half_rn(bce));
            hist[b][tid] = __hadd2(hist[b][tid], inc);     // b32 RMW + pk_add
        }
    };

    const long stride = (long)gridDim.x * BLOCK;
    long i = (long)blockIdx.x * BLOCK + tid;
    for (; i + stride < n4; i += 2 * stride) {             // 2x unroll for MLP
        float4 p0 = preds4[i];
        float4 t0 = targets4[i];
        float4 p1 = preds4[i + stride];
        float4 t1 = targets4[i + stride];
        do4(p0, t0);
        do4(p1, t1);
    }
    for (; i < n4; i += stride) do4(preds4[i], targets4[i]);

    // scalar tail (n_total % 4) — block 0, same private columns
    long tail0 = n4 * 4;
    if (blockIdx.x == 0 && tail0 + tid < n_total) {
        float x  = ((const float*)preds4)[tail0 + tid];
        float tt = ((const float*)targets4)[tail0 + tid];
        float y  = __builtin_fmaf(x * tt, -2.0f, x);
        float e  = fast_exp2(fabsf(y) * -LOG2E);
        float d  = 1.0f + e;
        float r  = fast_rcp(d);
        float g  = (y >= 0.0f) ? r : e * r;
        int   b  = (int)(g * 30.0f);
        b = (b > BINS - 1) ? BINS - 1 : b;
        float bce = fmaxf(y, 0.0f) + fast_log2(d) * LN2;
        hist[b][tid] = __hadd2(hist[b][tid],
                               __halves2half2(one_h, __float2half_rn(bce)));
    }
    __syncthreads();

    // tree-reduce 256 columns -> column 0 (packed v_pk_add_f16 adds;
    // block-level counts stay < 2048 -> exact integers in f16)
    for (int k = 7; k >= 0; --k) {
        int s = 1 << k;
        for (int i2 = tid; i2 < (BINS << k); i2 += BLOCK) {
            int b = i2 >> k;
            int c = i2 & (s - 1);
            hist[b][c] = __hadd2(hist[b][c], hist[b][c + s]);
        }
        __syncthreads();
    }

    // one padded f32 global atomic per {cnt,sum} per bin per block
    if (tid < BINS) {
        __half2 h = hist[tid][0];
        float cnt = __low2float(h);
        if (cnt != 0.0f) {
            atomicAdd(&gCnt[tid * GSTRIDE], cnt);
            atomicAdd(&gSum[tid * GSTRIDE], __high2float(h));
        }
    }
}

// loss = (1/n) * sum_b S_b / (0.75*acc_b + 0.25*cnt_b) over populated bins,
// n = max(#populated, 1)
__global__ void ghm_final(const float* __restrict__ gCnt,
                          const float* __restrict__ gSum,
                          const float* __restrict__ acc_sum,
                          float* __restrict__ out)
{
    int b = threadIdx.x;
    float val = 0.0f, nz = 0.0f;
    if (b < BINS) {
        float c = gCnt[b * GSTRIDE];
        if (c > 0.0f) {
            float na = 0.75f * acc_sum[b] + 0.25f * c;
            val = gSum[b * GSTRIDE] / na;
            nz  = 1.0f;
        }
    }
    #pragma unroll
    for (int m = 32; m >= 1; m >>= 1) {
        val += __shfl_xor(val, m);
        nz  += __shfl_xor(nz,  m);
    }
    if (b == 0) out[0] = val / fmaxf(nz, 1.0f);
}

extern "C" void kernel_launch(void* const* d_in, const int* in_sizes, int n_in,
                              void* d_out, int out_size, void* d_ws, size_t ws_size,
                              hipStream_t stream)
{
    const float* preds   = (const float*)d_in[0];
    const float* targets = (const float*)d_in[1];
    const float* acc_sum = (const float*)d_in[2];

    float* gCnt = (float*)d_ws;                 // slots 0..29, stride GSTRIDE
    float* gSum = gCnt + BINS * GSTRIDE;        // slots 0..29, stride GSTRIDE

    long n  = (long)in_sizes[0];
    long n4 = n / 4;

    // ws poisoned once, never re-poisoned: zero accumulators every call
    hipMemsetAsync(d_ws, 0, 2 * BINS * GSTRIDE * sizeof(float), stream);

    long want = (n4 + BLOCK - 1) / BLOCK;
    int blocks = (int)((want < GRID) ? (want > 1 ? want : 1) : GRID);

    ghm_pass1<<<blocks, BLOCK, 0, stream>>>((const float4*)preds,
                                            (const float4*)targets,
                                            n4, n, gCnt, gSum);
    ghm_final<<<1, 64, 0, stream>>>(gCnt, gSum, acc_sum, (float*)d_out);
}